// Round 3
// baseline (2580.443 us; speedup 1.0000x reference)
//
#include <hip/hip_runtime.h>
#include <math.h>

#define NPTS  10000
#define KNB   32
#define NCELL 216     // 6*6*6
#define NSGT  157     // ceil(NPTS/64) sort groups

// ---------------------------------------------------------------------------
// helpers
// ---------------------------------------------------------------------------
__device__ __forceinline__ float sgnf(float v) {
    return (v > 0.0f) ? 1.0f : ((v < 0.0f) ? -1.0f : 0.0f);
}

// Open3D ball->cube volume-preserving map, transcribed from the reference.
__device__ __forceinline__ void ball_to_cube(float x, float y, float z,
                                             float& X, float& Y, float& Z) {
    const float EPSF = 1e-12f;
    const float FOPI = (float)(4.0 / 3.14159265358979323846);
    float sq   = x * x + y * y + z * z;
    float norm = sqrtf(fmaxf(sq, EPSF));
    float rho2 = x * x + y * y;
    bool in_cone = (1.25f * z * z > rho2);
    float s1 = sqrtf(3.0f * norm / (norm + fabsf(z)));
    float s2 = norm / sqrtf(fmaxf(rho2, EPSF));
    float s  = in_cone ? s1 : s2;
    float xc = x * s;
    float yc = y * s;
    float zc = in_cone ? sgnf(z) * norm : 1.5f * z;
    if (sq < EPSF) { xc = 0.0f; yc = 0.0f; zc = 0.0f; }
    float sq_xy   = xc * xc + yc * yc;
    float norm_xy = sqrtf(fmaxf(sq_xy, EPSF));
    bool x_major = (fabsf(yc) <= fabsf(xc));
    float xd = (fabsf(xc) < EPSF) ? 1.0f : xc;
    float yd = (fabsf(yc) < EPSF) ? 1.0f : yc;
    float tx = sgnf(xc) * norm_xy;
    float ty = sgnf(yc) * norm_xy;
    float xq = x_major ? tx : ty * FOPI * atanf(xc / yd);
    float yq = x_major ? tx * FOPI * atanf(yc / xd) : ty;
    if (sq_xy < EPSF) { xq = 0.0f; yq = 0.0f; }
    X = xq; Y = yq; Z = zc;
}

// ---------------------------------------------------------------------------
// Kernel 1: per-(point,neighbor) geometry record + neighbor counts.
// Record (uint4): x,y,z = trilinear fracs (fp32 bits); w = packed:
//   [7:0]=c000 cell, [8]=dx?, [9]=dy?, [10]=dz?, [11]=valid, [25:12]=nidx
// ---------------------------------------------------------------------------
__global__ __launch_bounds__(256) void geom_kernel(
    const float* __restrict__ pos, const int* __restrict__ nidx,
    uint4* __restrict__ geo, float* __restrict__ cnt) {
    int t = blockIdx.x * 256 + threadIdx.x;
    if (t >= NPTS * KNB) return;
    int j = t >> 5;
    int k = t & 31;
    int nid = nidx[t];
    float px = pos[j * 3], py = pos[j * 3 + 1], pz = pos[j * 3 + 2];
    float qx = pos[nid * 3], qy = pos[nid * 3 + 1], qz = pos[nid * 3 + 2];
    // exact fp32 (no FMA contraction) to reproduce numpy's mask bit-for-bit
    float dx = __fsub_rn(px, qx), dy = __fsub_rn(py, qy), dz = __fsub_rn(pz, qz);
    float d2 = __fadd_rn(__fadd_rn(__fmul_rn(dx, dx), __fmul_rn(dy, dy)),
                         __fmul_rn(dz, dz));
    bool valid = (d2 <= 2.25f);
    if (valid && nid == 0) {
        for (int kk = 0; kk < k; ++kk) {
            if (nidx[j * KNB + kk] == 0) { valid = false; break; }
        }
    }
    uint4 g = make_uint4(0u, 0u, 0u, 0u);
    if (valid) {
        const float C = (float)(2.0 / 3.0);   // 2/EXTENT
        float ux = (qx - px) * C, uy = (qy - py) * C, uz = (qz - pz) * C;
        float X, Y, Z;
        ball_to_cube(ux, uy, uz, X, Y, Z);
        float cs[3] = { (X + 1.0f) * 2.5f, (Y + 1.0f) * 2.5f, (Z + 1.0f) * 2.5f };
        int i0[3], i1[3];
        float fr[3];
        #pragma unroll
        for (int d = 0; d < 3; ++d) {
            float f0 = floorf(cs[d]);
            fr[d] = cs[d] - f0;               // frac from UNCLIPPED floor (ref)
            int a = (int)f0;
            a = min(max(a, 0), 5);
            i0[d] = a;
            i1[d] = min(a + 1, 5);
        }
        int c000 = (i0[0] * 6 + i0[1]) * 6 + i0[2];
        unsigned bits = (unsigned)c000
                      | ((unsigned)(i1[0] - i0[0]) << 8)
                      | ((unsigned)(i1[1] - i0[1]) << 9)
                      | ((unsigned)(i1[2] - i0[2]) << 10)
                      | (1u << 11)
                      | ((unsigned)nid << 12);
        g.x = __float_as_uint(fr[0]);
        g.y = __float_as_uint(fr[1]);
        g.z = __float_as_uint(fr[2]);
        g.w = bits;
        atomicAdd(&cnt[j], 1.0f);
    }
    geo[t] = g;
}

// ---------------------------------------------------------------------------
// Kernel 2: counting sort of corner contributions by CELL per 64-pt sort
// group. Payload packs nid | ptl<<14 | cell<<20 so staging needs no other
// metadata. starts[sg][217] = per-cell prefix (cells contiguous -> any cell
// chunk is one contiguous stream slice). Built once, used by all 3 layers.
// ---------------------------------------------------------------------------
__global__ __launch_bounds__(256) void sort_kernel(
    const uint4* __restrict__ geo, uint2* __restrict__ contribs,
    int* __restrict__ starts) {
    __shared__ int hist[NCELL];
    __shared__ int pref[NCELL + 1];
    const int sg = blockIdx.x, tid = threadIdx.x;
    if (tid < NCELL) hist[tid] = 0;
    __syncthreads();
    const int npts = min(64, NPTS - sg * 64);
    const int nrec = npts * KNB;
    const uint4* gb = geo + (size_t)sg * 64 * KNB;
    for (int r = tid; r < nrec; r += 256) {
        uint4 g = gb[r];
        if (g.w & 2048u) {
            int c000 = g.w & 255u;
            int dxo = (g.w & 256u)  ? 36 : 0;
            int dyo = (g.w & 512u)  ? 6  : 0;
            int dzo = (g.w & 1024u) ? 1  : 0;
            #pragma unroll
            for (int c = 0; c < 8; ++c) {
                int cell = c000 + ((c & 4) ? dxo : 0) + ((c & 2) ? dyo : 0)
                                + ((c & 1) ? dzo : 0);
                atomicAdd(&hist[cell], 1);
            }
        }
    }
    __syncthreads();
    if (tid == 0) {
        int run = 0;
        for (int m = 0; m < NCELL; ++m) { pref[m] = run; run += hist[m]; }
        pref[NCELL] = run;
    }
    __syncthreads();
    for (int i = tid; i < NCELL + 1; i += 256)
        starts[sg * (NCELL + 1) + i] = pref[i];
    if (tid < NCELL) hist[tid] = pref[tid];   // cursors
    __syncthreads();
    uint2* cb = contribs + (size_t)sg * 16384;
    for (int r = tid; r < nrec; r += 256) {
        uint4 g = gb[r];
        if (g.w & 2048u) {
            int ptl = r >> 5;
            float fx = __uint_as_float(g.x);
            float fy = __uint_as_float(g.y);
            float fz = __uint_as_float(g.z);
            int c000 = g.w & 255u;
            int dxo = (g.w & 256u)  ? 36 : 0;
            int dyo = (g.w & 512u)  ? 6  : 0;
            int dzo = (g.w & 1024u) ? 1  : 0;
            int nid = (g.w >> 12) & 16383u;
            #pragma unroll
            for (int c = 0; c < 8; ++c) {
                float wgt = ((c & 4) ? fx : 1.f - fx)
                          * ((c & 2) ? fy : 1.f - fy)
                          * ((c & 1) ? fz : 1.f - fz);
                int cell = c000 + ((c & 4) ? dxo : 0) + ((c & 2) ? dyo : 0)
                                + ((c & 1) ? dzo : 0);
                int p = atomicAdd(&hist[cell], 1);
                cb[p] = make_uint2(__float_as_uint(wgt),
                                   (unsigned)nid | ((unsigned)ptl << 14)
                                                 | ((unsigned)cell << 20));
            }
        }
    }
}

// ---------------------------------------------------------------------------
// Kernel 3: conv as tiled GEMM. Block = MT pts x COUT. Per cell-chunk:
// cooperative A zero, then LANE-PARALLEL branch-free scatter: each CIN/4-lane
// group owns one contribution (coalesced float4 feats load + 4 ds_add_f32
// LDS atomics -- avg bucket size ~1, collisions rare). Then 4pt x 4co
// register-tile FMA GEMM from LDS with double-buffered W.
// K-split across blockIdx.y into partial buffers (combined later).
// ---------------------------------------------------------------------------
template<int CIN, int COUT, int CPC, int MT, int KSPLIT>
__global__ __launch_bounds__(256, 3) void conv_kernel(
    const float* __restrict__ feats, const float* __restrict__ W,
    const uint2* __restrict__ contribs, const int* __restrict__ starts,
    float* __restrict__ partial) {
    constexpr int KC   = CPC * CIN;       // K per chunk
    constexpr int ASTR = KC + 4;          // +4 pad (mult of 4 for float4)
    constexpr int CG   = COUT / 4;        // co groups
    constexpr int NSG  = MT / 64;         // sort groups per block (1 or 2)
    constexpr int NCHUNK = NCELL / CPC;
    constexpr int WPT  = (KC * COUT) / 1024;  // W float4s per thread
    constexpr int TPC  = CIN / 4;             // threads per contribution
    constexpr int GPB  = 256 / TPC;           // contributions in flight

    __shared__ alignas(16) float Al[MT * ASTR];
    __shared__ alignas(16) float Wl[2][KC * COUT];
    __shared__ int Sl[NSG][NCELL + 1];

    const int tid   = threadIdx.x;
    const int cg    = tid % CG;
    const int pg    = tid / CG;
    const int bx    = blockIdx.x;
    const int ks    = blockIdx.y;
    const int gslot = tid / TPC;
    const int ch    = tid % TPC;

    for (int s2 = 0; s2 < NSG; ++s2) {
        int sg = bx * NSG + s2;
        for (int i = tid; i < NCELL + 1; i += 256)
            Sl[s2][i] = (sg < NSGT) ? starts[sg * (NCELL + 1) + i] : 0;
    }

    const int c0 = NCHUNK * ks / KSPLIT;
    const int c1 = NCHUNK * (ks + 1) / KSPLIT;

    // stage chunk c: zero A tile, sync, lane-parallel atomic scatter
    auto stage = [&](int c) {
        float4 z4; z4.x = z4.y = z4.z = z4.w = 0.f;
        float4* Az = reinterpret_cast<float4*>(Al);
        #pragma unroll 4
        for (int i = tid; i < MT * (ASTR / 4); i += 256) Az[i] = z4;
        __syncthreads();   // also orders Sl load before first use
        const int cellbase = c * CPC;
        #pragma unroll
        for (int s2 = 0; s2 < NSG; ++s2) {
            const uint2* cbs = contribs + (size_t)(bx * NSG + s2) * 16384;
            const int s = Sl[s2][cellbase];
            const int e = Sl[s2][cellbase + CPC];
            for (int i = s + gslot; i < e; i += GPB) {
                uint2 rec = cbs[i];
                float wgt = __uint_as_float(rec.x);
                int nid = rec.y & 16383;
                int ptl = (rec.y >> 14) & 63;
                int cel = (rec.y >> 20);
                float4 f4 = *reinterpret_cast<const float4*>(
                    feats + (size_t)nid * CIN + ch * 4);
                float* dst = Al + (s2 * 64 + ptl) * ASTR
                           + (cel - cellbase) * CIN + ch * 4;
                atomicAdd(dst + 0, wgt * f4.x);
                atomicAdd(dst + 1, wgt * f4.y);
                atomicAdd(dst + 2, wgt * f4.z);
                atomicAdd(dst + 3, wgt * f4.w);
            }
        }
    };

    // prologue: W chunk c0 -> LDS, A chunk c0 staged
    {
        const float4* Wg = reinterpret_cast<const float4*>(W + (size_t)c0 * KC * COUT);
        float4* Wd = reinterpret_cast<float4*>(Wl[0]);
        #pragma unroll
        for (int j = 0; j < WPT; ++j) Wd[tid + j * 256] = Wg[tid + j * 256];
    }
    stage(c0);
    __syncthreads();

    float4 acc[4];
    #pragma unroll
    for (int p = 0; p < 4; ++p) { acc[p].x = acc[p].y = acc[p].z = acc[p].w = 0.f; }

    for (int c = c0; c < c1; ++c) {
        const int b = (c - c0) & 1;
        float4 wpre[WPT];
        if (c + 1 < c1) {
            const float4* Wg = reinterpret_cast<const float4*>(W + (size_t)(c + 1) * KC * COUT);
            #pragma unroll
            for (int j = 0; j < WPT; ++j) wpre[j] = Wg[tid + j * 256];
        }
        const float* Wb = Wl[b];
        #pragma unroll 2
        for (int g = 0; g < KC / 4; ++g) {
            float4 wf[4];
            #pragma unroll
            for (int j = 0; j < 4; ++j)
                wf[j] = *reinterpret_cast<const float4*>(Wb + (g * 4 + j) * COUT + cg * 4);
            float4 af[4];
            #pragma unroll
            for (int p = 0; p < 4; ++p)
                af[p] = *reinterpret_cast<const float4*>(Al + (pg * 4 + p) * ASTR + g * 4);
            #pragma unroll
            for (int p = 0; p < 4; ++p) {
                const float* afp = reinterpret_cast<const float*>(&af[p]);
                #pragma unroll
                for (int j = 0; j < 4; ++j) {
                    float a = afp[j];
                    acc[p].x = fmaf(a, wf[j].x, acc[p].x);
                    acc[p].y = fmaf(a, wf[j].y, acc[p].y);
                    acc[p].z = fmaf(a, wf[j].z, acc[p].z);
                    acc[p].w = fmaf(a, wf[j].w, acc[p].w);
                }
            }
        }
        __syncthreads();
        if (c + 1 < c1) {
            float4* Wd = reinterpret_cast<float4*>(Wl[b ^ 1]);
            #pragma unroll
            for (int j = 0; j < WPT; ++j) Wd[tid + j * 256] = wpre[j];
            stage(c + 1);
        }
        __syncthreads();
    }

    #pragma unroll
    for (int p = 0; p < 4; ++p) {
        int n = bx * MT + pg * 4 + p;
        if (n < NPTS)
            *reinterpret_cast<float4*>(partial + ((size_t)ks * NPTS + n) * COUT + cg * 4) = acc[p];
    }
}

// ---------------------------------------------------------------------------
// Kernel 4: combine K-split partials, normalize by neighbor count, bias, relu.
// ---------------------------------------------------------------------------
template<int COUT, int KSPLIT>
__global__ __launch_bounds__(256) void combine_kernel(
    const float* __restrict__ partial, const float* __restrict__ cnt,
    const float* __restrict__ bias, float* __restrict__ out) {
    int idx = blockIdx.x * 256 + threadIdx.x;
    if (idx >= NPTS * COUT) return;
    int n = idx / COUT, co = idx % COUT;
    float s = 0.f;
    #pragma unroll
    for (int k2 = 0; k2 < KSPLIT; ++k2)
        s += partial[((size_t)k2 * NPTS + n) * COUT + co];
    float c = cnt[n];
    if (c > 0.f) s /= fmaxf(c, 1.f);
    out[idx] = fmaxf(s + bias[co], 0.f);
}

// ---------------------------------------------------------------------------
// Kernel 5: fused FC chain. One wave per point, __shfl broadcasts.
// ---------------------------------------------------------------------------
__global__ __launch_bounds__(64) void fc_kernel(
    const float* __restrict__ x,
    const float* __restrict__ W1, const float* __restrict__ b1,
    const float* __restrict__ W2, const float* __restrict__ b2,
    const float* __restrict__ W3, const float* __restrict__ b3,
    const float* __restrict__ W4, const float* __restrict__ b4,
    float* __restrict__ out) {
    int n = blockIdx.x;
    int lane = threadIdx.x;
    float xv = (lane < 32) ? x[(size_t)n * 32 + lane] : 0.0f;

    float t = b1[lane];
    for (int ci = 0; ci < 32; ++ci)
        t = fmaf(__shfl(xv, ci), W1[ci * 64 + lane], t);
    float h1 = fmaxf(t, 0.0f);

    t = b2[lane];
    for (int ci = 0; ci < 64; ++ci)
        t = fmaf(__shfl(h1, ci), W2[ci * 64 + lane], t);
    float h2 = fmaxf(t, 0.0f);

    int l32 = lane & 31;
    t = b3[l32];
    for (int ci = 0; ci < 64; ++ci)
        t = fmaf(__shfl(h2, ci), W3[ci * 32 + l32], t);
    float h3 = fmaxf(t, 0.0f);

    int ch = (lane < 3) ? lane : 0;
    float o = b4[ch];
    for (int ci = 0; ci < 32; ++ci)
        o = fmaf(__shfl(h3, ci), W4[ci * 3 + ch], o);
    if (lane < 3) out[(size_t)n * 3 + lane] = o;
}

// ---------------------------------------------------------------------------
// launch
// ---------------------------------------------------------------------------
extern "C" void kernel_launch(void* const* d_in, const int* in_sizes, int n_in,
                              void* d_out, int out_size, void* d_ws, size_t ws_size,
                              hipStream_t stream) {
    const float* feats = (const float*)d_in[0];
    const float* pos   = (const float*)d_in[1];
    const int*   nidx  = (const int*)d_in[2];
    // d_in[3] (neighbor_mask) unused: mask recomputed exactly.
    const float* W1 = (const float*)d_in[4];
    const float* b1 = (const float*)d_in[5];
    const float* W2 = (const float*)d_in[6];
    const float* b2 = (const float*)d_in[7];
    const float* W3 = (const float*)d_in[8];
    const float* b3 = (const float*)d_in[9];
    const float* Wfc1 = (const float*)d_in[10];
    const float* bfc1 = (const float*)d_in[11];
    const float* Wfc2 = (const float*)d_in[12];
    const float* bfc2 = (const float*)d_in[13];
    const float* Wfc3 = (const float*)d_in[14];
    const float* bfc3 = (const float*)d_in[15];
    const float* Wout = (const float*)d_in[16];
    const float* bout = (const float*)d_in[17];

    char* ws = (char*)d_ws;
    uint2* contrib = (uint2*)(ws);                    // 20,578,304 B
    int*   starts  = (int*)  (ws + 20578304);         //    136,276 B
    float* cnt     = (float*)(ws + 20714624);         //     40,000 B
    float* x1      = (float*)(ws + 20754624);         //  2,560,000 B
    float* x2      = (float*)(ws + 23314624);         //  2,560,000 B
    float* x3      = (float*)(ws + 25874624);         //  1,280,000 B
    // geo (5.12 MB) is dead after sort_kernel; alias partial (10.24 MB) there
    uint4* geo     = (uint4*)(ws + 27154624);
    float* partial = (float*)(ws + 27154624);         // 10,240,000 B -> 37.4 MB total

    hipMemsetAsync(cnt, 0, NPTS * sizeof(float), stream);
    geom_kernel<<<(NPTS * KNB) / 256, 256, 0, stream>>>(pos, nidx, geo, cnt);
    sort_kernel<<<NSGT, 256, 0, stream>>>(geo, contrib, starts);

    conv_kernel<4, 64, 8, 64, 2><<<dim3(157, 2), 256, 0, stream>>>(
        feats, W1, contrib, starts, partial);
    combine_kernel<64, 2><<<(NPTS * 64 + 255) / 256, 256, 0, stream>>>(
        partial, cnt, b1, x1);

    conv_kernel<64, 64, 1, 64, 4><<<dim3(157, 4), 256, 0, stream>>>(
        x1, W2, contrib, starts, partial);
    combine_kernel<64, 4><<<(NPTS * 64 + 255) / 256, 256, 0, stream>>>(
        partial, cnt, b2, x2);

    conv_kernel<64, 32, 1, 128, 4><<<dim3(79, 4), 256, 0, stream>>>(
        x2, W3, contrib, starts, partial);
    combine_kernel<32, 4><<<(NPTS * 32 + 255) / 256, 256, 0, stream>>>(
        partial, cnt, b3, x3);

    fc_kernel<<<NPTS, 64, 0, stream>>>(x3, Wfc1, bfc1, Wfc2, bfc2,
                                       Wfc3, bfc3, Wout, bout, (float*)d_out);
}

// Round 4
// 2077.889 us; speedup vs baseline: 1.2419x; 1.2419x over previous
//
#include <hip/hip_runtime.h>
#include <math.h>

#define NPTS  10000
#define KNB   32
#define NCELL 216     // 6*6*6
#define NSGT  157     // ceil(NPTS/64) sort groups

// ---------------------------------------------------------------------------
// helpers
// ---------------------------------------------------------------------------
__device__ __forceinline__ float sgnf(float v) {
    return (v > 0.0f) ? 1.0f : ((v < 0.0f) ? -1.0f : 0.0f);
}

// Open3D ball->cube volume-preserving map, transcribed from the reference.
__device__ __forceinline__ void ball_to_cube(float x, float y, float z,
                                             float& X, float& Y, float& Z) {
    const float EPSF = 1e-12f;
    const float FOPI = (float)(4.0 / 3.14159265358979323846);
    float sq   = x * x + y * y + z * z;
    float norm = sqrtf(fmaxf(sq, EPSF));
    float rho2 = x * x + y * y;
    bool in_cone = (1.25f * z * z > rho2);
    float s1 = sqrtf(3.0f * norm / (norm + fabsf(z)));
    float s2 = norm / sqrtf(fmaxf(rho2, EPSF));
    float s  = in_cone ? s1 : s2;
    float xc = x * s;
    float yc = y * s;
    float zc = in_cone ? sgnf(z) * norm : 1.5f * z;
    if (sq < EPSF) { xc = 0.0f; yc = 0.0f; zc = 0.0f; }
    float sq_xy   = xc * xc + yc * yc;
    float norm_xy = sqrtf(fmaxf(sq_xy, EPSF));
    bool x_major = (fabsf(yc) <= fabsf(xc));
    float xd = (fabsf(xc) < EPSF) ? 1.0f : xc;
    float yd = (fabsf(yc) < EPSF) ? 1.0f : yc;
    float tx = sgnf(xc) * norm_xy;
    float ty = sgnf(yc) * norm_xy;
    float xq = x_major ? tx : ty * FOPI * atanf(xc / yd);
    float yq = x_major ? tx * FOPI * atanf(yc / xd) : ty;
    if (sq_xy < EPSF) { xq = 0.0f; yq = 0.0f; }
    X = xq; Y = yq; Z = zc;
}

// ---------------------------------------------------------------------------
// Kernel 1: per-(point,neighbor) geometry record + neighbor counts.
// Record (uint4): x,y,z = trilinear fracs (fp32 bits); w = packed:
//   [7:0]=c000 cell, [8]=dx?, [9]=dy?, [10]=dz?, [11]=valid, [25:12]=nidx
// ---------------------------------------------------------------------------
__global__ __launch_bounds__(256) void geom_kernel(
    const float* __restrict__ pos, const int* __restrict__ nidx,
    uint4* __restrict__ geo, float* __restrict__ cnt) {
    int t = blockIdx.x * 256 + threadIdx.x;
    if (t >= NPTS * KNB) return;
    int j = t >> 5;
    int k = t & 31;
    int nid = nidx[t];
    float px = pos[j * 3], py = pos[j * 3 + 1], pz = pos[j * 3 + 2];
    float qx = pos[nid * 3], qy = pos[nid * 3 + 1], qz = pos[nid * 3 + 2];
    // exact fp32 (no FMA contraction) to reproduce numpy's mask bit-for-bit
    float dx = __fsub_rn(px, qx), dy = __fsub_rn(py, qy), dz = __fsub_rn(pz, qz);
    float d2 = __fadd_rn(__fadd_rn(__fmul_rn(dx, dx), __fmul_rn(dy, dy)),
                         __fmul_rn(dz, dz));
    bool valid = (d2 <= 2.25f);
    if (valid && nid == 0) {
        for (int kk = 0; kk < k; ++kk) {
            if (nidx[j * KNB + kk] == 0) { valid = false; break; }
        }
    }
    uint4 g = make_uint4(0u, 0u, 0u, 0u);
    if (valid) {
        const float C = (float)(2.0 / 3.0);   // 2/EXTENT
        float ux = (qx - px) * C, uy = (qy - py) * C, uz = (qz - pz) * C;
        float X, Y, Z;
        ball_to_cube(ux, uy, uz, X, Y, Z);
        float cs[3] = { (X + 1.0f) * 2.5f, (Y + 1.0f) * 2.5f, (Z + 1.0f) * 2.5f };
        int i0[3], i1[3];
        float fr[3];
        #pragma unroll
        for (int d = 0; d < 3; ++d) {
            float f0 = floorf(cs[d]);
            fr[d] = cs[d] - f0;               // frac from UNCLIPPED floor (ref)
            int a = (int)f0;
            a = min(max(a, 0), 5);
            i0[d] = a;
            i1[d] = min(a + 1, 5);
        }
        int c000 = (i0[0] * 6 + i0[1]) * 6 + i0[2];
        unsigned bits = (unsigned)c000
                      | ((unsigned)(i1[0] - i0[0]) << 8)
                      | ((unsigned)(i1[1] - i0[1]) << 9)
                      | ((unsigned)(i1[2] - i0[2]) << 10)
                      | (1u << 11)
                      | ((unsigned)nid << 12);
        g.x = __float_as_uint(fr[0]);
        g.y = __float_as_uint(fr[1]);
        g.z = __float_as_uint(fr[2]);
        g.w = bits;
        atomicAdd(&cnt[j], 1.0f);
    }
    geo[t] = g;
}

// ---------------------------------------------------------------------------
// Kernel 2: counting sort of corner contributions by CELL per 64-pt sort
// group. Payload packs nid | ptl<<14 | cell<<20. starts[sg][217] = per-cell
// prefix. Built once, consumed by all 3 conv layers.
// ---------------------------------------------------------------------------
__global__ __launch_bounds__(256) void sort_kernel(
    const uint4* __restrict__ geo, uint2* __restrict__ contribs,
    int* __restrict__ starts) {
    __shared__ int hist[NCELL];
    __shared__ int pref[NCELL + 1];
    const int sg = blockIdx.x, tid = threadIdx.x;
    if (tid < NCELL) hist[tid] = 0;
    __syncthreads();
    const int npts = min(64, NPTS - sg * 64);
    const int nrec = npts * KNB;
    const uint4* gb = geo + (size_t)sg * 64 * KNB;
    for (int r = tid; r < nrec; r += 256) {
        uint4 g = gb[r];
        if (g.w & 2048u) {
            int c000 = g.w & 255u;
            int dxo = (g.w & 256u)  ? 36 : 0;
            int dyo = (g.w & 512u)  ? 6  : 0;
            int dzo = (g.w & 1024u) ? 1  : 0;
            #pragma unroll
            for (int c = 0; c < 8; ++c) {
                int cell = c000 + ((c & 4) ? dxo : 0) + ((c & 2) ? dyo : 0)
                                + ((c & 1) ? dzo : 0);
                atomicAdd(&hist[cell], 1);
            }
        }
    }
    __syncthreads();
    if (tid == 0) {
        int run = 0;
        for (int m = 0; m < NCELL; ++m) { pref[m] = run; run += hist[m]; }
        pref[NCELL] = run;
    }
    __syncthreads();
    for (int i = tid; i < NCELL + 1; i += 256)
        starts[sg * (NCELL + 1) + i] = pref[i];
    if (tid < NCELL) hist[tid] = pref[tid];   // cursors
    __syncthreads();
    uint2* cb = contribs + (size_t)sg * 16384;
    for (int r = tid; r < nrec; r += 256) {
        uint4 g = gb[r];
        if (g.w & 2048u) {
            int ptl = r >> 5;
            float fx = __uint_as_float(g.x);
            float fy = __uint_as_float(g.y);
            float fz = __uint_as_float(g.z);
            int c000 = g.w & 255u;
            int dxo = (g.w & 256u)  ? 36 : 0;
            int dyo = (g.w & 512u)  ? 6  : 0;
            int dzo = (g.w & 1024u) ? 1  : 0;
            int nid = (g.w >> 12) & 16383u;
            #pragma unroll
            for (int c = 0; c < 8; ++c) {
                float wgt = ((c & 4) ? fx : 1.f - fx)
                          * ((c & 2) ? fy : 1.f - fy)
                          * ((c & 1) ? fz : 1.f - fz);
                int cell = c000 + ((c & 4) ? dxo : 0) + ((c & 2) ? dyo : 0)
                                + ((c & 1) ? dzo : 0);
                int p = atomicAdd(&hist[cell], 1);
                cb[p] = make_uint2(__float_as_uint(wgt),
                                   (unsigned)nid | ((unsigned)ptl << 14)
                                                 | ((unsigned)cell << 20));
            }
        }
    }
}

// ---------------------------------------------------------------------------
// Kernel 3: conv as A-in-LDS / W-wave-uniform GEMM.
// Block = 64 pts (1 sort group) x COUT; COUT/8 waves, wave w owns cos
// 8w..8w+7 (wave-uniform W address -> scalar/broadcast loads from L1, W
// never touches LDS or VGPR-heavy tiles). lane = pt; 8 acc per thread.
// A-tile (64 x KC, stride KC+4 -> conflict-free b128) double-buffered in LDS;
// scatter of chunk c+1 (float4 gather + 4 LDS atomics per contribution)
// overlaps GEMM of chunk c. K-split over blockIdx.y into partial buffers.
// ---------------------------------------------------------------------------
template<int CIN, int COUT, int CPC, int KSPLIT>
__global__ __launch_bounds__(COUT * 8, 6) void conv_kernel(
    const float* __restrict__ feats, const float* __restrict__ W,
    const uint2* __restrict__ contribs, const int* __restrict__ starts,
    float* __restrict__ partial) {
    constexpr int KC   = CPC * CIN;        // K per chunk
    constexpr int ASTR = KC + 4;           // quad-stride 1 mod 8: b128-clean
    constexpr int BT   = COUT * 8;         // threads (512 or 256)
    constexpr int NCHUNK = NCELL / CPC;
    constexpr int TPC  = CIN / 4;          // threads per contribution
    constexpr int GPB  = BT / TPC;         // contributions in flight

    __shared__ alignas(16) float Ab[2][64 * ASTR];

    const int tid   = threadIdx.x;
    const int lane  = tid & 63;
    const int wvid  = __builtin_amdgcn_readfirstlane(tid >> 6);
    const int cow   = wvid * 8;            // wave-uniform co base
    const int bx    = blockIdx.x;          // sort group
    const int ks    = blockIdx.y;
    const int gslot = tid / TPC;
    const int ch    = tid % TPC;

    const uint2* cbs = contribs + (size_t)bx * 16384;
    const int*   st  = starts + bx * (NCELL + 1);

    const int c0 = NCHUNK * ks / KSPLIT;
    const int c1 = NCHUNK * (ks + 1) / KSPLIT;

    auto zero = [&](int b) {
        float4 z; z.x = z.y = z.z = z.w = 0.f;
        float4* p = reinterpret_cast<float4*>(Ab[b]);
        #pragma unroll 2
        for (int i = tid; i < 64 * ASTR / 4; i += BT) p[i] = z;
    };
    auto scatter = [&](int c, int b) {
        const int s = st[c * CPC], e = st[c * CPC + CPC];
        const int cb4 = c * CPC;
        for (int i = s + gslot; i < e; i += GPB) {
            uint2 rec = cbs[i];
            float wgt = __uint_as_float(rec.x);
            int nid = rec.y & 16383;
            int ptl = (rec.y >> 14) & 63;
            int cel = (int)(rec.y >> 20);
            float4 f4 = *reinterpret_cast<const float4*>(
                feats + (size_t)nid * CIN + ch * 4);
            float* dst = &Ab[b][ptl * ASTR + (cel - cb4) * CIN + ch * 4];
            atomicAdd(dst + 0, wgt * f4.x);
            atomicAdd(dst + 1, wgt * f4.y);
            atomicAdd(dst + 2, wgt * f4.z);
            atomicAdd(dst + 3, wgt * f4.w);
        }
    };

    zero(0); zero(1);
    __syncthreads();
    scatter(c0, 0);
    __syncthreads();

    float acc[8];
    #pragma unroll
    for (int j = 0; j < 8; ++j) acc[j] = 0.f;

    for (int c = c0; c < c1; ++c) {
        const int b = (c - c0) & 1;
        if (c + 1 < c1) scatter(c + 1, b ^ 1);   // overlaps GEMM below
        const float* Wc = W + (size_t)c * CPC * CIN * COUT;  // k-major, stride COUT
        const float* Ar = Ab[b] + lane * ASTR;
        #pragma unroll 4
        for (int g = 0; g < KC / 4; ++g) {
            float4 a4 = *reinterpret_cast<const float4*>(Ar + g * 4);
            const float av[4] = { a4.x, a4.y, a4.z, a4.w };
            #pragma unroll
            for (int j = 0; j < 4; ++j) {
                float4 w0 = *reinterpret_cast<const float4*>(
                    Wc + (size_t)(g * 4 + j) * COUT + cow);
                float4 w1 = *reinterpret_cast<const float4*>(
                    Wc + (size_t)(g * 4 + j) * COUT + cow + 4);
                float a = av[j];
                acc[0] = fmaf(a, w0.x, acc[0]);
                acc[1] = fmaf(a, w0.y, acc[1]);
                acc[2] = fmaf(a, w0.z, acc[2]);
                acc[3] = fmaf(a, w0.w, acc[3]);
                acc[4] = fmaf(a, w1.x, acc[4]);
                acc[5] = fmaf(a, w1.y, acc[5]);
                acc[6] = fmaf(a, w1.z, acc[6]);
                acc[7] = fmaf(a, w1.w, acc[7]);
            }
        }
        __syncthreads();
        zero(b);          // recycle buf b for chunk c+2
        __syncthreads();
    }

    const int n = bx * 64 + lane;
    if (n < NPTS) {
        float* po = partial + ((size_t)ks * NPTS + n) * COUT + cow;
        *reinterpret_cast<float4*>(po)     = make_float4(acc[0], acc[1], acc[2], acc[3]);
        *reinterpret_cast<float4*>(po + 4) = make_float4(acc[4], acc[5], acc[6], acc[7]);
    }
}

// ---------------------------------------------------------------------------
// Kernel 4: combine K-split partials, normalize by neighbor count, bias, relu.
// ---------------------------------------------------------------------------
template<int COUT, int KSPLIT>
__global__ __launch_bounds__(256) void combine_kernel(
    const float* __restrict__ partial, const float* __restrict__ cnt,
    const float* __restrict__ bias, float* __restrict__ out) {
    int idx = blockIdx.x * 256 + threadIdx.x;
    if (idx >= NPTS * COUT) return;
    int n = idx / COUT, co = idx % COUT;
    float s = 0.f;
    #pragma unroll
    for (int k2 = 0; k2 < KSPLIT; ++k2)
        s += partial[((size_t)k2 * NPTS + n) * COUT + co];
    float c = cnt[n];
    if (c > 0.f) s /= fmaxf(c, 1.f);
    out[idx] = fmaxf(s + bias[co], 0.f);
}

// ---------------------------------------------------------------------------
// Kernel 5: fused FC chain. One wave per point, __shfl broadcasts.
// ---------------------------------------------------------------------------
__global__ __launch_bounds__(64) void fc_kernel(
    const float* __restrict__ x,
    const float* __restrict__ W1, const float* __restrict__ b1,
    const float* __restrict__ W2, const float* __restrict__ b2,
    const float* __restrict__ W3, const float* __restrict__ b3,
    const float* __restrict__ W4, const float* __restrict__ b4,
    float* __restrict__ out) {
    int n = blockIdx.x;
    int lane = threadIdx.x;
    float xv = (lane < 32) ? x[(size_t)n * 32 + lane] : 0.0f;

    float t = b1[lane];
    for (int ci = 0; ci < 32; ++ci)
        t = fmaf(__shfl(xv, ci), W1[ci * 64 + lane], t);
    float h1 = fmaxf(t, 0.0f);

    t = b2[lane];
    for (int ci = 0; ci < 64; ++ci)
        t = fmaf(__shfl(h1, ci), W2[ci * 64 + lane], t);
    float h2 = fmaxf(t, 0.0f);

    int l32 = lane & 31;
    t = b3[l32];
    for (int ci = 0; ci < 64; ++ci)
        t = fmaf(__shfl(h2, ci), W3[ci * 32 + l32], t);
    float h3 = fmaxf(t, 0.0f);

    int ch = (lane < 3) ? lane : 0;
    float o = b4[ch];
    for (int ci = 0; ci < 32; ++ci)
        o = fmaf(__shfl(h3, ci), W4[ci * 3 + ch], o);
    if (lane < 3) out[(size_t)n * 3 + lane] = o;
}

// ---------------------------------------------------------------------------
// launch
// ---------------------------------------------------------------------------
extern "C" void kernel_launch(void* const* d_in, const int* in_sizes, int n_in,
                              void* d_out, int out_size, void* d_ws, size_t ws_size,
                              hipStream_t stream) {
    const float* feats = (const float*)d_in[0];
    const float* pos   = (const float*)d_in[1];
    const int*   nidx  = (const int*)d_in[2];
    // d_in[3] (neighbor_mask) unused: mask recomputed exactly.
    const float* W1 = (const float*)d_in[4];
    const float* b1 = (const float*)d_in[5];
    const float* W2 = (const float*)d_in[6];
    const float* b2 = (const float*)d_in[7];
    const float* W3 = (const float*)d_in[8];
    const float* b3 = (const float*)d_in[9];
    const float* Wfc1 = (const float*)d_in[10];
    const float* bfc1 = (const float*)d_in[11];
    const float* Wfc2 = (const float*)d_in[12];
    const float* bfc2 = (const float*)d_in[13];
    const float* Wfc3 = (const float*)d_in[14];
    const float* bfc3 = (const float*)d_in[15];
    const float* Wout = (const float*)d_in[16];
    const float* bout = (const float*)d_in[17];

    char* ws = (char*)d_ws;
    uint2* contrib = (uint2*)(ws);                    // 20,578,304 B
    int*   starts  = (int*)  (ws + 20578304);         //    136,276 B
    float* cnt     = (float*)(ws + 20714624);         //     40,000 B
    float* x1      = (float*)(ws + 20754624);         //  2,560,000 B
    float* x2      = (float*)(ws + 23314624);         //  2,560,000 B
    float* x3      = (float*)(ws + 25874624);         //  1,280,000 B
    // geo (5.12 MB) dead after sort -> alias with partial region
    uint4* geo     = (uint4*)(ws + 27154624);
    float* partial = (float*)(ws + 27154624);

    // big layout: conv2 KSPLIT=8 needs 8*2.56 MB = 20.48 MB partial region
    const bool big = ws_size >= (size_t)47634624;

    hipMemsetAsync(cnt, 0, NPTS * sizeof(float), stream);
    geom_kernel<<<(NPTS * KNB) / 256, 256, 0, stream>>>(pos, nidx, geo, cnt);
    sort_kernel<<<NSGT, 256, 0, stream>>>(geo, contrib, starts);

    // conv1: CIN=4, COUT=64, CPC=8 (KC=32), KSPLIT=4 -> partial 10.24 MB
    conv_kernel<4, 64, 8, 4><<<dim3(NSGT, 4), 512, 0, stream>>>(
        feats, W1, contrib, starts, partial);
    combine_kernel<64, 4><<<(NPTS * 64 + 255) / 256, 256, 0, stream>>>(
        partial, cnt, b1, x1);

    // conv2: CIN=64, COUT=64, CPC=1 (KC=64)
    if (big) {
        conv_kernel<64, 64, 1, 8><<<dim3(NSGT, 8), 512, 0, stream>>>(
            x1, W2, contrib, starts, partial);
        combine_kernel<64, 8><<<(NPTS * 64 + 255) / 256, 256, 0, stream>>>(
            partial, cnt, b2, x2);
    } else {
        conv_kernel<64, 64, 1, 4><<<dim3(NSGT, 4), 512, 0, stream>>>(
            x1, W2, contrib, starts, partial);
        combine_kernel<64, 4><<<(NPTS * 64 + 255) / 256, 256, 0, stream>>>(
            partial, cnt, b2, x2);
    }

    // conv3: CIN=64, COUT=32, CPC=1, KSPLIT=8 -> partial 10.24 MB
    conv_kernel<64, 32, 1, 8><<<dim3(NSGT, 8), 256, 0, stream>>>(
        x2, W3, contrib, starts, partial);
    combine_kernel<32, 8><<<(NPTS * 32 + 255) / 256, 256, 0, stream>>>(
        partial, cnt, b3, x3);

    fc_kernel<<<NPTS, 64, 0, stream>>>(x3, Wfc1, bfc1, Wfc2, bfc2,
                                       Wfc3, bfc3, Wout, bout, (float*)d_out);
}